// Round 15
// baseline (3887.291 us; speedup 1.0000x reference)
//
#include <hip/hip_runtime.h>

#define LEAKY(v) ((v) >= 0.f ? (v) : 0.01f * (v))

#define CS   4608      // ring channel stride in floats (18 rows * 256)
#define ZS1  294912    // ring tower stride (64 * CS)
#define TSL  16        // top-pad slot
#define BSL  17        // bottom-pad slot
#define EBCS 7936      // ebuf channel stride (31*256)
#define NWG  128
#define S16(c) ((c) & 15)

// ================= bootstrap kernels (validated, from round 14) =================
__global__ __launch_bounds__(256, 2) void conv3B(
    const float* __restrict__ ebuf,
    const float* __restrict__ W0, const float* __restrict__ B0,
    const float* __restrict__ W1, const float* __restrict__ B1,
    float* __restrict__ out)
{
    const int lane = threadIdx.x & 63;
    const int wv   = threadIdx.x >> 6;
    const int h  = blockIdx.y;
    const int cq = blockIdx.z & 3;
    const int z  = blockIdx.z >> 2;
    const int cout0 = cq * 16 + wv * 4;
    const float* W  = (z ? W1 : W0) + cout0 * 27;
    const float* Bv = z ? B1 : B0;

    float a[4][4] = {};
    #pragma unroll
    for (int kh = 0; kh < 3; ++kh) {
        const int r = h - 1 + kh;
        const bool valid = (r >= 0 && r < 15);
        const float msk = valid ? 1.f : 0.f;
        #pragma unroll
        for (int c = 0; c < 3; ++c) {
            const float* rr = ebuf + c * EBCS + (valid ? r : 0) * 256 + lane * 4;
            float4 v = *(const float4*)rr;
            v.x *= msk; v.y *= msk; v.z *= msk; v.w *= msk;
            float wl = __shfl_up(v.w, 1);   if (lane == 0)  wl = 0.f;
            float wr = __shfl_down(v.x, 1); if (lane == 63) wr = 0.f;
            const float win[6] = {wl, v.x, v.y, v.z, v.w, wr};
            #pragma unroll
            for (int j = 0; j < 4; ++j) {
                const float* wj = W + j * 27 + c * 9 + kh * 3;
                #pragma unroll
                for (int cc = 0; cc < 4; ++cc)
                    a[j][cc] += wj[0] * win[cc] + wj[1] * win[cc + 1] + wj[2] * win[cc + 2];
            }
        }
    }
    const int slot = (h == 0) ? TSL : (h == 14 ? BSL : (h & 15));
    float* o = out + (size_t)z * ZS1 + slot * 256;
    #pragma unroll
    for (int j = 0; j < 4; ++j) {
        const float bb = Bv[cout0 + j];
        float4 r4;
        r4.x = LEAKY(a[j][0] + bb); r4.y = LEAKY(a[j][1] + bb);
        r4.z = LEAKY(a[j][2] + bb); r4.w = LEAKY(a[j][3] + bb);
        *(float4*)(o + (cout0 + j) * CS + lane * 4) = r4;
    }
}

template<int HOUT, int HIN, int OFFI, int OFFO, int NZ>
__global__ __launch_bounds__(256, 2) void convYB(
    const float* __restrict__ in,
    const float* __restrict__ W0, const float* __restrict__ B0,
    const float* __restrict__ W1, const float* __restrict__ B1,
    float* __restrict__ out)
{
    const int lane = threadIdx.x;
    const int y    = threadIdx.y;
    const int h  = blockIdx.y;
    const int gz = blockIdx.z;
    const int z    = (NZ == 2) ? (gz >> 6) : 0;
    const int cout = (NZ == 2) ? (gz & 63) : gz;
    const float* W  = (z ? W1 : W0) + cout * 576 + y * 144;
    const float* Bv = z ? B1 : B0;
    const float* ib = in + (size_t)z * ZS1 + y * 16 * CS + lane * 4;

    int slot[3];
    #pragma unroll
    for (int t = 0; t < 3; ++t) {
        const int g = h + t;
        slot[t] = (g == 0) ? TSL : (g == HIN - 1 ? BSL : ((g + OFFI) & 15));
    }

    float acc[4] = {};
    #pragma unroll 4
    for (int c = 0; c < 16; ++c) {
        #pragma unroll
        for (int t = 0; t < 3; ++t) {
            float4 v = *(const float4*)(ib + c * CS + slot[t] * 256);
            float wl = __shfl_up(v.w, 1);   if (lane == 0)  wl = 0.f;
            float wr = __shfl_down(v.x, 1); if (lane == 63) wr = 0.f;
            const float win[6] = {wl, v.x, v.y, v.z, v.w, wr};
            const float* wj = W + c * 9 + t * 3;
            #pragma unroll
            for (int cc = 0; cc < 4; ++cc)
                acc[cc] += wj[0] * win[cc] + wj[1] * win[cc + 1] + wj[2] * win[cc + 2];
        }
    }

    __shared__ float red[4][256];
    *(float4*)&red[y][lane * 4] = *(float4*)acc;
    __syncthreads();
    const int col = y * 64 + lane;
    const int os = (h == 0) ? TSL : (h == HOUT - 1 ? BSL : ((h + OFFO) & 15));
    float v = Bv[cout] + red[0][col] + red[1][col] + red[2][col] + red[3][col];
    out[(size_t)z * ZS1 + cout * CS + os * 256 + col] = LEAKY(v);
}

__global__ __launch_bounds__(256, 2) void mmB(const float* __restrict__ L4R,
                                              float* __restrict__ MMR)
{
    const int col = threadIdx.x;
    const int r   = blockIdx.x;
    const int ig  = blockIdx.y;
    const int slot = (r == 0) ? TSL : (r == 8 ? BSL : ((r + 3) & 15));
    const float* s = L4R + slot * 256 + col;
    const float* e = L4R + ZS1 + slot * 256 + col;
    float sv[64];
    #pragma unroll
    for (int c = 0; c < 64; ++c) sv[c] = s[c * CS];
    float ev[8];
    #pragma unroll
    for (int j = 0; j < 8; ++j) ev[j] = e[(ig * 8 + j) * CS];
    #pragma unroll
    for (int k = 0; k < 8; ++k) {
        float acc = 0.f;
        #pragma unroll
        for (int j = 0; j < 8; ++j) acc += ev[j] * sv[j * 8 + k];
        MMR[(ig * 8 + k) * CS + slot * 256 + col] = acc;
    }
}

// ================= persistent stepper =================
struct SP {
    const float *x;
    const float *w1x, *b1x, *w2x, *b2x, *w3x, *b3x, *w4x, *b4x;
    const float *w1e, *b1e, *w2e, *b2e, *w3e, *b3e, *w4e, *b4e;
    const float *w5, *b5, *w6, *b6, *w7, *b7, *w8, *b8, *w9, *b9;
    float *ebuf, *L1R, *L2R, *L3R, *L4R, *MMR, *L5R, *L6R, *L7b, *L8b, *preds, *out;
    unsigned *bar;
};

// Grid barrier v2: RELAXED polling (no per-poll L2 invalidate — round 2's bug),
// one release fence before arrival, one acquire fence after the flag flips.
__device__ __forceinline__ void gbar(unsigned* cnt, unsigned* gen)
{
    __syncthreads();   // all waves drain vmcnt before s_barrier -> WG stores in L2
    if (threadIdx.x == 0 && threadIdx.y == 0) {
        __threadfence();   // release: write back this XCD's L2 once
        unsigned g = __hip_atomic_load(gen, __ATOMIC_RELAXED, __HIP_MEMORY_SCOPE_AGENT);
        unsigned v = __hip_atomic_fetch_add(cnt, 1u, __ATOMIC_ACQ_REL, __HIP_MEMORY_SCOPE_AGENT);
        if (v == NWG - 1) {
            __hip_atomic_store(cnt, 0u, __ATOMIC_RELAXED, __HIP_MEMORY_SCOPE_AGENT);
            __hip_atomic_store(gen, g + 1u, __ATOMIC_RELEASE, __HIP_MEMORY_SCOPE_AGENT);
        } else {
            while (__hip_atomic_load(gen, __ATOMIC_RELAXED, __HIP_MEMORY_SCOPE_AGENT) == g)
                __builtin_amdgcn_s_sleep(8);
        }
        __threadfence();   // acquire: invalidate stale lines once
    }
    __syncthreads();
}

// one fresh conv row: (64,4) block; identical math to round-14 convInc
__device__ __forceinline__ void convRowD(
    const float* __restrict__ t0, const float* __restrict__ t1, const float* __restrict__ t2,
    const float* __restrict__ W, float bb, float* __restrict__ orow, int ics,
    float (*red)[256])
{
    const int lane = threadIdx.x, y = threadIdx.y;
    const float* Wy = W + y * 144;
    const int yo = y * 16 * ics + lane * 4;
    const float* p0 = t0 + yo;
    const float* p1 = t1 + yo;
    const float* p2 = t2 + yo;

    float acc[4] = {};
    #pragma unroll 4
    for (int c = 0; c < 16; ++c) {
        #pragma unroll
        for (int t = 0; t < 3; ++t) {
            const float* rp = (t == 0 ? p0 : (t == 1 ? p1 : p2)) + c * ics;
            float4 v = *(const float4*)rp;
            float wl = __shfl_up(v.w, 1);   if (lane == 0)  wl = 0.f;
            float wr = __shfl_down(v.x, 1); if (lane == 63) wr = 0.f;
            const float win[6] = {wl, v.x, v.y, v.z, v.w, wr};
            const float* wj = Wy + c * 9 + t * 3;
            #pragma unroll
            for (int cc = 0; cc < 4; ++cc)
                acc[cc] += wj[0] * win[cc] + wj[1] * win[cc + 1] + wj[2] * win[cc + 2];
        }
    }
    __syncthreads();   // previous iteration's red readers done
    *(float4*)&red[y][lane * 4] = *(float4*)acc;
    __syncthreads();
    const int col = y * 64 + lane;
    float v = bb + red[0][col] + red[1][col] + red[2][col] + red[3][col];
    orow[col] = LEAKY(v);
}

__device__ __forceinline__ void phaseL1(const SP& p, int i, int wg)
{
    const int lane = threadIdx.x, wv = threadIdx.y;
    for (int vb = wg; vb < 24; vb += NWG) {
        const int job = vb >> 3, cq = vb & 3, z = (vb >> 2) & 1;
        const float* taps[3];
        int os;
        if (job == 0)      { taps[0] = nullptr;                  taps[1] = p.ebuf + i * 256;        taps[2] = p.ebuf + (i + 1) * 256;  os = TSL; }
        else if (job == 1) { taps[0] = p.ebuf + (i + 13) * 256;  taps[1] = p.ebuf + (i + 14) * 256; taps[2] = nullptr;                 os = BSL; }
        else               { taps[0] = p.ebuf + (i + 12) * 256;  taps[1] = p.ebuf + (i + 13) * 256; taps[2] = p.ebuf + (i + 14) * 256; os = S16(i + 13); }
        const int cout0 = cq * 16 + wv * 4;
        const float* W  = (z ? p.w1e : p.w1x) + cout0 * 27;
        const float* Bv = z ? p.b1e : p.b1x;

        float a[4][4] = {};
        #pragma unroll
        for (int t = 0; t < 3; ++t) {
            const float* rp = taps[t];
            if (rp) {
                #pragma unroll
                for (int c = 0; c < 3; ++c) {
                    float4 v = *(const float4*)(rp + c * EBCS + lane * 4);
                    float wl = __shfl_up(v.w, 1);   if (lane == 0)  wl = 0.f;
                    float wr = __shfl_down(v.x, 1); if (lane == 63) wr = 0.f;
                    const float win[6] = {wl, v.x, v.y, v.z, v.w, wr};
                    #pragma unroll
                    for (int j = 0; j < 4; ++j) {
                        const float* wj = W + j * 27 + c * 9 + t * 3;
                        #pragma unroll
                        for (int cc = 0; cc < 4; ++cc)
                            a[j][cc] += wj[0] * win[cc] + wj[1] * win[cc + 1] + wj[2] * win[cc + 2];
                    }
                }
            }
        }
        float* o = p.L1R + (size_t)z * ZS1 + os * 256;
        #pragma unroll
        for (int j = 0; j < 4; ++j) {
            const float bb = Bv[cout0 + j];
            float4 r4;
            r4.x = LEAKY(a[j][0] + bb); r4.y = LEAKY(a[j][1] + bb);
            r4.z = LEAKY(a[j][2] + bb); r4.w = LEAKY(a[j][3] + bb);
            *(float4*)(o + (cout0 + j) * CS + lane * 4) = r4;
        }
    }
}

__device__ __forceinline__ void phase2t(
    int i, int d, const float* inR, float* outR,
    const float* W0, const float* B0, const float* W1, const float* B1,
    int wg, float (*red)[256])
{
    for (int vb = wg; vb < 384; vb += NWG) {
        const int cout = vb & 63, q = vb >> 6;
        const int z = q & 1, jt = q >> 1;
        const float* base = inR + (size_t)z * ZS1;
        const float* t0; const float* t1; const float* t2; int os;
        if (jt == 0)      { t0 = base + TSL * 256;              t1 = base + S16(i + d) * 256;      t2 = base + S16(i + d + 1) * 256;  os = TSL; }
        else if (jt == 1) { t0 = base + S16(i + 13 - d) * 256;  t1 = base + S16(i + 14 - d) * 256; t2 = base + BSL * 256;             os = BSL; }
        else              { t0 = base + S16(i + 12 - d) * 256;  t1 = base + S16(i + 13 - d) * 256; t2 = base + S16(i + 14 - d) * 256; os = S16(i + 13 - d); }
        convRowD(t0, t1, t2, (z ? W1 : W0) + cout * 576, (z ? B1 : B0)[cout],
                 outR + (size_t)z * ZS1 + cout * CS + os * 256, CS, red);
    }
}

__device__ __forceinline__ void phase1t(
    int i, int d, const float* inR, float* outR,
    const float* W, const float* B, int wg, float (*red)[256])
{
    for (int vb = wg; vb < 192; vb += NWG) {
        const int cout = vb & 63, jt = vb >> 6;
        const float* t0; const float* t1; const float* t2; int os;
        if (jt == 0)      { t0 = inR + TSL * 256;              t1 = inR + S16(i + d) * 256;      t2 = inR + S16(i + d + 1) * 256;  os = TSL; }
        else if (jt == 1) { t0 = inR + S16(i + 13 - d) * 256;  t1 = inR + S16(i + 14 - d) * 256; t2 = inR + BSL * 256;             os = BSL; }
        else              { t0 = inR + S16(i + 12 - d) * 256;  t1 = inR + S16(i + 13 - d) * 256; t2 = inR + S16(i + 14 - d) * 256; os = S16(i + 13 - d); }
        convRowD(t0, t1, t2, W + cout * 576, B[cout],
                 outR + cout * CS + os * 256, CS, red);
    }
}

__device__ __forceinline__ void phaseMM(const SP& p, int i, int wg)
{
    const int col = threadIdx.y * 64 + threadIdx.x;
    for (int vb = wg; vb < 24; vb += NWG) {
        const int job = vb >> 3, ig = vb & 7;
        const int slot = (job == 0) ? TSL : (job == 1 ? BSL : S16(i + 10));
        const float* s = p.L4R + slot * 256 + col;
        const float* e = p.L4R + ZS1 + slot * 256 + col;
        float sv[64];
        #pragma unroll
        for (int c = 0; c < 64; ++c) sv[c] = s[c * CS];
        float ev[8];
        #pragma unroll
        for (int j = 0; j < 8; ++j) ev[j] = e[(ig * 8 + j) * CS];
        #pragma unroll
        for (int k = 0; k < 8; ++k) {
            float acc = 0.f;
            #pragma unroll
            for (int j = 0; j < 8; ++j) acc += ev[j] * sv[j * 8 + k];
            p.MMR[(ig * 8 + k) * CS + slot * 256 + col] = acc;
        }
    }
}

__device__ __forceinline__ void phaseL7(const SP& p, int i, int wg, float (*red)[256])
{
    for (int vb = wg; vb < 192; vb += NWG) {
        const int cout = vb & 63, jt = vb >> 6;
        const float* t0; const float* t1; const float* t2;
        if (jt == 0)      { t0 = p.L6R + TSL * 256;          t1 = p.L6R + S16(i + 6) * 256; t2 = p.L6R + S16(i + 7) * 256; }
        else if (jt == 1) { t0 = p.L6R + S16(i + 6) * 256;   t1 = p.L6R + S16(i + 7) * 256; t2 = p.L6R + S16(i + 8) * 256; }
        else              { t0 = p.L6R + S16(i + 7) * 256;   t1 = p.L6R + S16(i + 8) * 256; t2 = p.L6R + BSL * 256; }
        convRowD(t0, t1, t2, p.w7 + cout * 576, p.b7[cout],
                 p.L7b + jt * 256 + cout * 768, CS, red);
    }
}

__device__ __forceinline__ void phaseL8(const SP& p, int wg, float (*red)[256])
{
    for (int vb = wg; vb < 64; vb += NWG) {
        convRowD(p.L7b, p.L7b + 256, p.L7b + 512, p.w8 + vb * 576, p.b8[vb],
                 p.L8b + vb * 256, 768, red);
    }
}

__device__ __forceinline__ void dC9(const SP& p, int i)
{
    const int col = threadIdx.y * 64 + threadIdx.x;
    const bool mL = (col > 0), mR = (col < 255);
    float a0 = 0.f, a1 = 0.f, a2 = 0.f;
    #pragma unroll 4
    for (int cin = 0; cin < 64; ++cin) {
        const float* r_ = p.L8b + cin * 256;
        float vm = mL ? r_[col - 1] : 0.f;
        float v0 = r_[col];
        float vp = mR ? r_[col + 1] : 0.f;
        const float* wk0 = p.w9 + (0 * 64 + cin) * 9 + 3;
        const float* wk1 = p.w9 + (1 * 64 + cin) * 9 + 3;
        const float* wk2 = p.w9 + (2 * 64 + cin) * 9 + 3;
        a0 += vm * wk0[0] + v0 * wk0[1] + vp * wk0[2];
        a1 += vm * wk1[0] + v0 * wk1[1] + vp * wk1[2];
        a2 += vm * wk2[0] + v0 * wk2[1] + vp * wk2[2];
    }
    const float av[3] = {a0, a1, a2};
    #pragma unroll
    for (int j = 0; j < 3; ++j) {
        float v = LEAKY(p.b9[j] + av[j]);
        p.preds[i * 768 + j * 256 + col] = v;
        p.ebuf[j * EBCS + (15 + i) * 256 + col] =
            p.x[j * EBCS + (15 + i) * 256 + col] - v;
    }
}

__global__ __launch_bounds__(256, 2) void stepper(SP p)
{
    __shared__ float red[4][256];
    const int wg = blockIdx.x;
    const int flat = threadIdx.y * 64 + threadIdx.x;
    unsigned* cnt = p.bar;
    unsigned* gen = p.bar + 32;

    // step 0 tail (bootstrap covered L1..L6)
    phaseL7(p, 0, wg, red);  gbar(cnt, gen);
    phaseL8(p, wg, red);     gbar(cnt, gen);
    if (wg == 0) dC9(p, 0);  gbar(cnt, gen);

    for (int i = 1; i < 16; ++i) {
        phaseL1(p, i, wg);                                                gbar(cnt, gen);
        phase2t(i, 1, p.L1R, p.L2R, p.w2x, p.b2x, p.w2e, p.b2e, wg, red); gbar(cnt, gen);
        phase2t(i, 2, p.L2R, p.L3R, p.w3x, p.b3x, p.w3e, p.b3e, wg, red); gbar(cnt, gen);
        phase2t(i, 3, p.L3R, p.L4R, p.w4x, p.b4x, p.w4e, p.b4e, wg, red); gbar(cnt, gen);
        phaseMM(p, i, wg);                                                gbar(cnt, gen);
        phase1t(i, 4, p.MMR, p.L5R, p.w5, p.b5, wg, red);                 gbar(cnt, gen);
        phase1t(i, 5, p.L5R, p.L6R, p.w6, p.b6, wg, red);                 gbar(cnt, gen);
        phaseL7(p, i, wg, red);                                           gbar(cnt, gen);
        phaseL8(p, wg, red);                                              gbar(cnt, gen);
        if (wg == 0) dC9(p, i);                                           gbar(cnt, gen);
    }

    // finalize: d_out = [pred (3,16,256) | truth (3,16,256)]
    for (int idx = wg * 256 + flat; idx < 24576; idx += NWG * 256) {
        if (idx < 12288) {
            const int c = idx >> 12;
            const int t = (idx >> 8) & 15;
            const int w = idx & 255;
            p.out[idx] = p.preds[t * 768 + c * 256 + w];
        } else {
            const int j = idx - 12288;
            const int c = j >> 12;
            const int t = (j >> 8) & 15;
            const int w = j & 255;
            p.out[idx] = p.ebuf[c * EBCS + (15 + t) * 256 + w];
        }
    }
}

extern "C" void kernel_launch(void* const* d_in, const int* in_sizes, int n_in,
                              void* d_out, int out_size, void* d_ws, size_t ws_size,
                              hipStream_t stream)
{
    SP p;
    p.x   = (const float*)d_in[0];
    p.w1x = (const float*)d_in[1];  p.b1x = (const float*)d_in[2];
    p.w2x = (const float*)d_in[3];  p.b2x = (const float*)d_in[4];
    p.w3x = (const float*)d_in[5];  p.b3x = (const float*)d_in[6];
    p.w4x = (const float*)d_in[7];  p.b4x = (const float*)d_in[8];
    p.w1e = (const float*)d_in[9];  p.b1e = (const float*)d_in[10];
    p.w2e = (const float*)d_in[11]; p.b2e = (const float*)d_in[12];
    p.w3e = (const float*)d_in[13]; p.b3e = (const float*)d_in[14];
    p.w4e = (const float*)d_in[15]; p.b4e = (const float*)d_in[16];
    p.w5  = (const float*)d_in[17]; p.b5  = (const float*)d_in[18];
    p.w6  = (const float*)d_in[19]; p.b6  = (const float*)d_in[20];
    p.w7  = (const float*)d_in[21]; p.b7  = (const float*)d_in[22];
    p.w8  = (const float*)d_in[23]; p.b8  = (const float*)d_in[24];
    p.w9  = (const float*)d_in[25]; p.b9  = (const float*)d_in[26];

    float* ws = (float*)d_ws;
    p.ebuf  = ws;                     // 23808
    p.L1R   = p.ebuf + 23808;         // 2*ZS1
    p.L2R   = p.L1R + 589824;
    p.L3R   = p.L2R + 589824;
    p.L4R   = p.L3R + 589824;
    p.MMR   = p.L4R + 589824;         // ZS1 (single)
    p.L5R   = p.MMR + 294912;
    p.L6R   = p.L5R + 294912;
    p.L7b   = p.L6R + 294912;         // 64*768
    p.L8b   = p.L7b + 49152;          // 16384
    p.preds = p.L8b + 16384;          // 12288
    p.bar   = (unsigned*)(p.preds + 12288);
    p.out   = (float*)d_out;

    hipMemsetAsync(p.bar, 0, 64 * sizeof(unsigned), stream);
    hipMemcpyAsync(p.ebuf, p.x, 23808 * sizeof(float), hipMemcpyDeviceToDevice, stream);

    const dim3 cb(64, 4);
    conv3B<<<dim3(1, 15, 8), 256, 0, stream>>>(p.ebuf, p.w1x, p.b1x, p.w1e, p.b1e, p.L1R);
    convYB<13, 15, 0, 1, 2><<<dim3(1, 13, 128), cb, 0, stream>>>(p.L1R, p.w2x, p.b2x, p.w2e, p.b2e, p.L2R);
    convYB<11, 13, 1, 2, 2><<<dim3(1, 11, 128), cb, 0, stream>>>(p.L2R, p.w3x, p.b3x, p.w3e, p.b3e, p.L3R);
    convYB<9, 11, 2, 3, 2><<<dim3(1, 9, 128), cb, 0, stream>>>(p.L3R, p.w4x, p.b4x, p.w4e, p.b4e, p.L4R);
    mmB<<<dim3(9, 8), 256, 0, stream>>>(p.L4R, p.MMR);
    convYB<7, 9, 3, 4, 1><<<dim3(1, 7, 64), cb, 0, stream>>>(p.MMR, p.w5, p.b5, p.w5, p.b5, p.L5R);
    convYB<5, 7, 4, 5, 1><<<dim3(1, 5, 64), cb, 0, stream>>>(p.L5R, p.w6, p.b6, p.w6, p.b6, p.L6R);

    stepper<<<NWG, cb, 0, stream>>>(p);
}

// Round 16
// 3638.744 us; speedup vs baseline: 1.0683x; 1.0683x over previous
//
#include <hip/hip_runtime.h>

#define LEAKY(v) ((v) >= 0.f ? (v) : 0.01f * (v))

#define CS   4608      // ring channel stride in floats (18 rows * 256)
#define ZS1  294912    // ring tower stride (64 * CS)
#define TSL  16        // top-pad slot
#define BSL  17        // bottom-pad slot
#define EBCS 7936      // ebuf channel stride (31*256)
#define NWG  128
#define S16(c) ((c) & 15)

// ================= bootstrap kernels (validated, from round 14) =================
__global__ __launch_bounds__(256, 2) void conv3B(
    const float* __restrict__ ebuf,
    const float* __restrict__ W0, const float* __restrict__ B0,
    const float* __restrict__ W1, const float* __restrict__ B1,
    float* __restrict__ out)
{
    const int lane = threadIdx.x & 63;
    const int wv   = threadIdx.x >> 6;
    const int h  = blockIdx.y;
    const int cq = blockIdx.z & 3;
    const int z  = blockIdx.z >> 2;
    const int cout0 = cq * 16 + wv * 4;
    const float* W  = (z ? W1 : W0) + cout0 * 27;
    const float* Bv = z ? B1 : B0;

    float a[4][4] = {};
    #pragma unroll
    for (int kh = 0; kh < 3; ++kh) {
        const int r = h - 1 + kh;
        const bool valid = (r >= 0 && r < 15);
        const float msk = valid ? 1.f : 0.f;
        #pragma unroll
        for (int c = 0; c < 3; ++c) {
            const float* rr = ebuf + c * EBCS + (valid ? r : 0) * 256 + lane * 4;
            float4 v = *(const float4*)rr;
            v.x *= msk; v.y *= msk; v.z *= msk; v.w *= msk;
            float wl = __shfl_up(v.w, 1);   if (lane == 0)  wl = 0.f;
            float wr = __shfl_down(v.x, 1); if (lane == 63) wr = 0.f;
            const float win[6] = {wl, v.x, v.y, v.z, v.w, wr};
            #pragma unroll
            for (int j = 0; j < 4; ++j) {
                const float* wj = W + j * 27 + c * 9 + kh * 3;
                #pragma unroll
                for (int cc = 0; cc < 4; ++cc)
                    a[j][cc] += wj[0] * win[cc] + wj[1] * win[cc + 1] + wj[2] * win[cc + 2];
            }
        }
    }
    const int slot = (h == 0) ? TSL : (h == 14 ? BSL : (h & 15));
    float* o = out + (size_t)z * ZS1 + slot * 256;
    #pragma unroll
    for (int j = 0; j < 4; ++j) {
        const float bb = Bv[cout0 + j];
        float4 r4;
        r4.x = LEAKY(a[j][0] + bb); r4.y = LEAKY(a[j][1] + bb);
        r4.z = LEAKY(a[j][2] + bb); r4.w = LEAKY(a[j][3] + bb);
        *(float4*)(o + (cout0 + j) * CS + lane * 4) = r4;
    }
}

template<int HOUT, int HIN, int OFFI, int OFFO, int NZ>
__global__ __launch_bounds__(256, 2) void convYB(
    const float* __restrict__ in,
    const float* __restrict__ W0, const float* __restrict__ B0,
    const float* __restrict__ W1, const float* __restrict__ B1,
    float* __restrict__ out)
{
    const int lane = threadIdx.x;
    const int y    = threadIdx.y;
    const int h  = blockIdx.y;
    const int gz = blockIdx.z;
    const int z    = (NZ == 2) ? (gz >> 6) : 0;
    const int cout = (NZ == 2) ? (gz & 63) : gz;
    const float* W  = (z ? W1 : W0) + cout * 576 + y * 144;
    const float* Bv = z ? B1 : B0;
    const float* ib = in + (size_t)z * ZS1 + y * 16 * CS + lane * 4;

    int slot[3];
    #pragma unroll
    for (int t = 0; t < 3; ++t) {
        const int g = h + t;
        slot[t] = (g == 0) ? TSL : (g == HIN - 1 ? BSL : ((g + OFFI) & 15));
    }

    float acc[4] = {};
    #pragma unroll 4
    for (int c = 0; c < 16; ++c) {
        #pragma unroll
        for (int t = 0; t < 3; ++t) {
            float4 v = *(const float4*)(ib + c * CS + slot[t] * 256);
            float wl = __shfl_up(v.w, 1);   if (lane == 0)  wl = 0.f;
            float wr = __shfl_down(v.x, 1); if (lane == 63) wr = 0.f;
            const float win[6] = {wl, v.x, v.y, v.z, v.w, wr};
            const float* wj = W + c * 9 + t * 3;
            #pragma unroll
            for (int cc = 0; cc < 4; ++cc)
                acc[cc] += wj[0] * win[cc] + wj[1] * win[cc + 1] + wj[2] * win[cc + 2];
        }
    }

    __shared__ float red[4][256];
    *(float4*)&red[y][lane * 4] = *(float4*)acc;
    __syncthreads();
    const int col = y * 64 + lane;
    const int os = (h == 0) ? TSL : (h == HOUT - 1 ? BSL : ((h + OFFO) & 15));
    float v = Bv[cout] + red[0][col] + red[1][col] + red[2][col] + red[3][col];
    out[(size_t)z * ZS1 + cout * CS + os * 256 + col] = LEAKY(v);
}

__global__ __launch_bounds__(256, 2) void mmB(const float* __restrict__ L4R,
                                              float* __restrict__ MMR)
{
    const int col = threadIdx.x;
    const int r   = blockIdx.x;
    const int ig  = blockIdx.y;
    const int slot = (r == 0) ? TSL : (r == 8 ? BSL : ((r + 3) & 15));
    const float* s = L4R + slot * 256 + col;
    const float* e = L4R + ZS1 + slot * 256 + col;
    float sv[64];
    #pragma unroll
    for (int c = 0; c < 64; ++c) sv[c] = s[c * CS];
    float ev[8];
    #pragma unroll
    for (int j = 0; j < 8; ++j) ev[j] = e[(ig * 8 + j) * CS];
    #pragma unroll
    for (int k = 0; k < 8; ++k) {
        float acc = 0.f;
        #pragma unroll
        for (int j = 0; j < 8; ++j) acc += ev[j] * sv[j * 8 + k];
        MMR[(ig * 8 + k) * CS + slot * 256 + col] = acc;
    }
}

// ================= persistent stepper =================
struct SP {
    const float *x;
    const float *w1x, *b1x, *w2x, *b2x, *w3x, *b3x, *w4x, *b4x;
    const float *w1e, *b1e, *w2e, *b2e, *w3e, *b3e, *w4e, *b4e;
    const float *w5, *b5, *w6, *b6, *w7, *b7, *w8, *b8, *w9, *b9;
    float *ebuf, *L1R, *L2R, *L3R, *L4R, *MMR, *L5R, *L6R, *L7b, *L8b, *preds, *out;
    unsigned *bar;
};

// Grid barrier: RELAXED polling; one release fence before arrival, one
// acquire fence after the flag flips. Weights live in LDS -> the L2
// invalidate no longer forces a 1.5 MB serial-s_load refetch per phase.
__device__ __forceinline__ void gbar(unsigned* cnt, unsigned* gen)
{
    __syncthreads();
    if (threadIdx.x == 0 && threadIdx.y == 0) {
        __threadfence();   // release
        unsigned g = __hip_atomic_load(gen, __ATOMIC_RELAXED, __HIP_MEMORY_SCOPE_AGENT);
        unsigned v = __hip_atomic_fetch_add(cnt, 1u, __ATOMIC_ACQ_REL, __HIP_MEMORY_SCOPE_AGENT);
        if (v == NWG - 1) {
            __hip_atomic_store(cnt, 0u, __ATOMIC_RELAXED, __HIP_MEMORY_SCOPE_AGENT);
            __hip_atomic_store(gen, g + 1u, __ATOMIC_RELEASE, __HIP_MEMORY_SCOPE_AGENT);
        } else {
            while (__hip_atomic_load(gen, __ATOMIC_RELAXED, __HIP_MEMORY_SCOPE_AGENT) == g)
                __builtin_amdgcn_s_sleep(2);
        }
        __threadfence();   // acquire
    }
    __syncthreads();
}

// one fresh conv row; W points into LDS (weights), bb from LDS
__device__ __forceinline__ void convRowD(
    const float* __restrict__ t0, const float* __restrict__ t1, const float* __restrict__ t2,
    const float* W, float bb, float* __restrict__ orow, int ics,
    float (*red)[256])
{
    const int lane = threadIdx.x, y = threadIdx.y;
    const float* Wy = W + y * 144;
    const int yo = y * 16 * ics + lane * 4;
    const float* p0 = t0 + yo;
    const float* p1 = t1 + yo;
    const float* p2 = t2 + yo;

    float acc[4] = {};
    #pragma unroll 4
    for (int c = 0; c < 16; ++c) {
        #pragma unroll
        for (int t = 0; t < 3; ++t) {
            const float* rp = (t == 0 ? p0 : (t == 1 ? p1 : p2)) + c * ics;
            float4 v = *(const float4*)rp;
            float wl = __shfl_up(v.w, 1);   if (lane == 0)  wl = 0.f;
            float wr = __shfl_down(v.x, 1); if (lane == 63) wr = 0.f;
            const float win[6] = {wl, v.x, v.y, v.z, v.w, wr};
            const float* wj = Wy + c * 9 + t * 3;
            #pragma unroll
            for (int cc = 0; cc < 4; ++cc)
                acc[cc] += wj[0] * win[cc] + wj[1] * win[cc + 1] + wj[2] * win[cc + 2];
        }
    }
    __syncthreads();
    *(float4*)&red[y][lane * 4] = *(float4*)acc;
    __syncthreads();
    const int col = y * 64 + lane;
    float v = bb + red[0][col] + red[1][col] + red[2][col] + red[3][col];
    orow[col] = LEAKY(v);
}

__device__ __forceinline__ void phaseL1(const SP& p, int i, int wg,
                                        const float* wl1, const float* bb1)
{
    const int lane = threadIdx.x, wv = threadIdx.y;
    for (int vb = wg; vb < 24; vb += NWG) {
        const int job = vb >> 3, z = (vb >> 2) & 1;
        const float* taps[3];
        int os;
        if (job == 0)      { taps[0] = nullptr;                  taps[1] = p.ebuf + i * 256;        taps[2] = p.ebuf + (i + 1) * 256;  os = TSL; }
        else if (job == 1) { taps[0] = p.ebuf + (i + 13) * 256;  taps[1] = p.ebuf + (i + 14) * 256; taps[2] = nullptr;                 os = BSL; }
        else               { taps[0] = p.ebuf + (i + 12) * 256;  taps[1] = p.ebuf + (i + 13) * 256; taps[2] = p.ebuf + (i + 14) * 256; os = S16(i + 13); }
        const int cq = vb & 3;
        const int cout0 = cq * 16 + wv * 4;
        const float* W = wl1 + (wv * 4) * 27;   // LDS slice holds couts cq*16..+15

        float a[4][4] = {};
        #pragma unroll
        for (int t = 0; t < 3; ++t) {
            const float* rp = taps[t];
            if (rp) {
                #pragma unroll
                for (int c = 0; c < 3; ++c) {
                    float4 v = *(const float4*)(rp + c * EBCS + lane * 4);
                    float wl = __shfl_up(v.w, 1);   if (lane == 0)  wl = 0.f;
                    float wr = __shfl_down(v.x, 1); if (lane == 63) wr = 0.f;
                    const float win[6] = {wl, v.x, v.y, v.z, v.w, wr};
                    #pragma unroll
                    for (int j = 0; j < 4; ++j) {
                        const float* wj = W + j * 27 + c * 9 + t * 3;
                        #pragma unroll
                        for (int cc = 0; cc < 4; ++cc)
                            a[j][cc] += wj[0] * win[cc] + wj[1] * win[cc + 1] + wj[2] * win[cc + 2];
                    }
                }
            }
        }
        float* o = p.L1R + (size_t)z * ZS1 + os * 256;
        #pragma unroll
        for (int j = 0; j < 4; ++j) {
            const float bb = bb1[wv * 4 + j];
            float4 r4;
            r4.x = LEAKY(a[j][0] + bb); r4.y = LEAKY(a[j][1] + bb);
            r4.z = LEAKY(a[j][2] + bb); r4.w = LEAKY(a[j][3] + bb);
            *(float4*)(o + (cout0 + j) * CS + lane * 4) = r4;
        }
    }
}

// NWG=128: wg<64 -> z=0 (jt 0,1,2); wg>=64 -> z=1. cout = wg&63 for all units.
__device__ __forceinline__ void phase2t(
    int i, int d, const float* inR, float* outR,
    const float* Wl, float bbv, int wg, float (*red)[256])
{
    for (int vb = wg; vb < 384; vb += NWG) {
        const int cout = vb & 63, q = vb >> 6;
        const int z = q & 1, jt = q >> 1;
        const float* base = inR + (size_t)z * ZS1;
        const float* t0; const float* t1; const float* t2; int os;
        if (jt == 0)      { t0 = base + TSL * 256;              t1 = base + S16(i + d) * 256;      t2 = base + S16(i + d + 1) * 256;  os = TSL; }
        else if (jt == 1) { t0 = base + S16(i + 13 - d) * 256;  t1 = base + S16(i + 14 - d) * 256; t2 = base + BSL * 256;             os = BSL; }
        else              { t0 = base + S16(i + 12 - d) * 256;  t1 = base + S16(i + 13 - d) * 256; t2 = base + S16(i + 14 - d) * 256; os = S16(i + 13 - d); }
        convRowD(t0, t1, t2, Wl, bbv,
                 outR + (size_t)z * ZS1 + cout * CS + os * 256, CS, red);
    }
}

__device__ __forceinline__ void phase1t(
    int i, int d, const float* inR, float* outR,
    const float* Wl, float bbv, int wg, float (*red)[256])
{
    for (int vb = wg; vb < 192; vb += NWG) {
        const int cout = vb & 63, jt = vb >> 6;
        const float* t0; const float* t1; const float* t2; int os;
        if (jt == 0)      { t0 = inR + TSL * 256;              t1 = inR + S16(i + d) * 256;      t2 = inR + S16(i + d + 1) * 256;  os = TSL; }
        else if (jt == 1) { t0 = inR + S16(i + 13 - d) * 256;  t1 = inR + S16(i + 14 - d) * 256; t2 = inR + BSL * 256;             os = BSL; }
        else              { t0 = inR + S16(i + 12 - d) * 256;  t1 = inR + S16(i + 13 - d) * 256; t2 = inR + S16(i + 14 - d) * 256; os = S16(i + 13 - d); }
        convRowD(t0, t1, t2, Wl, bbv,
                 outR + cout * CS + os * 256, CS, red);
    }
}

__device__ __forceinline__ void phaseMM(const SP& p, int i, int wg)
{
    const int col = threadIdx.y * 64 + threadIdx.x;
    for (int vb = wg; vb < 24; vb += NWG) {
        const int job = vb >> 3, ig = vb & 7;
        const int slot = (job == 0) ? TSL : (job == 1 ? BSL : S16(i + 10));
        const float* s = p.L4R + slot * 256 + col;
        const float* e = p.L4R + ZS1 + slot * 256 + col;
        float sv[64];
        #pragma unroll
        for (int c = 0; c < 64; ++c) sv[c] = s[c * CS];
        float ev[8];
        #pragma unroll
        for (int j = 0; j < 8; ++j) ev[j] = e[(ig * 8 + j) * CS];
        #pragma unroll
        for (int k = 0; k < 8; ++k) {
            float acc = 0.f;
            #pragma unroll
            for (int j = 0; j < 8; ++j) acc += ev[j] * sv[j * 8 + k];
            p.MMR[(ig * 8 + k) * CS + slot * 256 + col] = acc;
        }
    }
}

__device__ __forceinline__ void phaseL7(const SP& p, int i, const float* Wl, float bbv,
                                        int wg, float (*red)[256])
{
    for (int vb = wg; vb < 192; vb += NWG) {
        const int cout = vb & 63, jt = vb >> 6;
        const float* t0; const float* t1; const float* t2;
        if (jt == 0)      { t0 = p.L6R + TSL * 256;          t1 = p.L6R + S16(i + 6) * 256; t2 = p.L6R + S16(i + 7) * 256; }
        else if (jt == 1) { t0 = p.L6R + S16(i + 6) * 256;   t1 = p.L6R + S16(i + 7) * 256; t2 = p.L6R + S16(i + 8) * 256; }
        else              { t0 = p.L6R + S16(i + 7) * 256;   t1 = p.L6R + S16(i + 8) * 256; t2 = p.L6R + BSL * 256; }
        convRowD(t0, t1, t2, Wl, bbv,
                 p.L7b + jt * 256 + cout * 768, CS, red);
    }
}

__device__ __forceinline__ void phaseL8(const SP& p, const float* Wl, float bbv,
                                        int wg, float (*red)[256])
{
    for (int vb = wg; vb < 64; vb += NWG) {
        convRowD(p.L7b, p.L7b + 256, p.L7b + 512, Wl, bbv,
                 p.L8b + vb * 256, 768, red);
    }
}

__device__ __forceinline__ void dC9(const SP& p, int i, const float* wl9, const float* bb9)
{
    const int col = threadIdx.y * 64 + threadIdx.x;
    const bool mL = (col > 0), mR = (col < 255);
    float a0 = 0.f, a1 = 0.f, a2 = 0.f;
    #pragma unroll 4
    for (int cin = 0; cin < 64; ++cin) {
        const float* r_ = p.L8b + cin * 256;
        float vm = mL ? r_[col - 1] : 0.f;
        float v0 = r_[col];
        float vp = mR ? r_[col + 1] : 0.f;
        const float* wk0 = wl9 + (0 * 64 + cin) * 9 + 3;
        const float* wk1 = wl9 + (1 * 64 + cin) * 9 + 3;
        const float* wk2 = wl9 + (2 * 64 + cin) * 9 + 3;
        a0 += vm * wk0[0] + v0 * wk0[1] + vp * wk0[2];
        a1 += vm * wk1[0] + v0 * wk1[1] + vp * wk1[2];
        a2 += vm * wk2[0] + v0 * wk2[1] + vp * wk2[2];
    }
    const float av[3] = {a0, a1, a2};
    #pragma unroll
    for (int j = 0; j < 3; ++j) {
        float v = LEAKY(bb9[j] + av[j]);
        p.preds[i * 768 + j * 256 + col] = v;
        p.ebuf[j * EBCS + (15 + i) * 256 + col] =
            p.x[j * EBCS + (15 + i) * 256 + col] - v;
    }
}

__global__ __launch_bounds__(256, 2) void stepper(SP p)
{
    __shared__ float red[4][256];       // 4 KB
    __shared__ float wl[7 * 576];       // 15.75 KB: L2,L3,L4(tower z) + L5,L6,L7,L8 for cout=wg&63
    __shared__ float wl1[432];          // 1.7 KB (wg<24)
    __shared__ float wl9[1728];         // 6.75 KB (wg 0)
    __shared__ float bbs[8];
    __shared__ float bb1[16];
    __shared__ float bb9[3];

    const int wg = blockIdx.x;
    const int flat = threadIdx.y * 64 + threadIdx.x;
    unsigned* cnt = p.bar;
    unsigned* gen = p.bar + 32;

    // ---- one-time weight preload into LDS (immune to L2 invalidates) ----
    const int zt = wg >> 6;       // tower for L2-L4
    const int co = wg & 63;       // this wg's cout for conv phases
    for (int k = flat; k < 576; k += 256) {
        wl[0 * 576 + k] = (zt ? p.w2e : p.w2x)[co * 576 + k];
        wl[1 * 576 + k] = (zt ? p.w3e : p.w3x)[co * 576 + k];
        wl[2 * 576 + k] = (zt ? p.w4e : p.w4x)[co * 576 + k];
        wl[3 * 576 + k] = p.w5[co * 576 + k];
        wl[4 * 576 + k] = p.w6[co * 576 + k];
        wl[5 * 576 + k] = p.w7[co * 576 + k];
        wl[6 * 576 + k] = p.w8[co * 576 + k];
    }
    if (wg < 24) {
        const int z1 = (wg >> 2) & 1, cq = wg & 3;
        for (int k = flat; k < 432; k += 256)
            wl1[k] = (z1 ? p.w1e : p.w1x)[cq * 16 * 27 + k];
        if (flat < 16) bb1[flat] = (z1 ? p.b1e : p.b1x)[cq * 16 + flat];
    }
    if (wg == 0) {
        for (int k = flat; k < 1728; k += 256) wl9[k] = p.w9[k];
        if (flat < 3) bb9[flat] = p.b9[flat];
    }
    if (flat == 0) {
        bbs[0] = (zt ? p.b2e : p.b2x)[co];
        bbs[1] = (zt ? p.b3e : p.b3x)[co];
        bbs[2] = (zt ? p.b4e : p.b4x)[co];
        bbs[3] = p.b5[co];
        bbs[4] = p.b6[co];
        bbs[5] = p.b7[co];
        bbs[6] = p.b8[co];
    }
    __syncthreads();

    // step 0 tail (bootstrap covered L1..L6)
    phaseL7(p, 0, wl + 5 * 576, bbs[5], wg, red);  gbar(cnt, gen);
    phaseL8(p, wl + 6 * 576, bbs[6], wg, red);     gbar(cnt, gen);
    if (wg == 0) dC9(p, 0, wl9, bb9);              gbar(cnt, gen);

    for (int i = 1; i < 16; ++i) {
        phaseL1(p, i, wg, wl1, bb1);                                    gbar(cnt, gen);
        phase2t(i, 1, p.L1R, p.L2R, wl + 0 * 576, bbs[0], wg, red);     gbar(cnt, gen);
        phase2t(i, 2, p.L2R, p.L3R, wl + 1 * 576, bbs[1], wg, red);     gbar(cnt, gen);
        phase2t(i, 3, p.L3R, p.L4R, wl + 2 * 576, bbs[2], wg, red);     gbar(cnt, gen);
        phaseMM(p, i, wg);                                              gbar(cnt, gen);
        phase1t(i, 4, p.MMR, p.L5R, wl + 3 * 576, bbs[3], wg, red);     gbar(cnt, gen);
        phase1t(i, 5, p.L5R, p.L6R, wl + 4 * 576, bbs[4], wg, red);     gbar(cnt, gen);
        phaseL7(p, i, wl + 5 * 576, bbs[5], wg, red);                   gbar(cnt, gen);
        phaseL8(p, wl + 6 * 576, bbs[6], wg, red);                      gbar(cnt, gen);
        if (wg == 0) dC9(p, i, wl9, bb9);                               gbar(cnt, gen);
    }

    // finalize: d_out = [pred (3,16,256) | truth (3,16,256)]
    for (int idx = wg * 256 + flat; idx < 24576; idx += NWG * 256) {
        if (idx < 12288) {
            const int c = idx >> 12;
            const int t = (idx >> 8) & 15;
            const int w = idx & 255;
            p.out[idx] = p.preds[t * 768 + c * 256 + w];
        } else {
            const int j = idx - 12288;
            const int c = j >> 12;
            const int t = (j >> 8) & 15;
            const int w = j & 255;
            p.out[idx] = p.ebuf[c * EBCS + (15 + t) * 256 + w];
        }
    }
}

extern "C" void kernel_launch(void* const* d_in, const int* in_sizes, int n_in,
                              void* d_out, int out_size, void* d_ws, size_t ws_size,
                              hipStream_t stream)
{
    SP p;
    p.x   = (const float*)d_in[0];
    p.w1x = (const float*)d_in[1];  p.b1x = (const float*)d_in[2];
    p.w2x = (const float*)d_in[3];  p.b2x = (const float*)d_in[4];
    p.w3x = (const float*)d_in[5];  p.b3x = (const float*)d_in[6];
    p.w4x = (const float*)d_in[7];  p.b4x = (const float*)d_in[8];
    p.w1e = (const float*)d_in[9];  p.b1e = (const float*)d_in[10];
    p.w2e = (const float*)d_in[11]; p.b2e = (const float*)d_in[12];
    p.w3e = (const float*)d_in[13]; p.b3e = (const float*)d_in[14];
    p.w4e = (const float*)d_in[15]; p.b4e = (const float*)d_in[16];
    p.w5  = (const float*)d_in[17]; p.b5  = (const float*)d_in[18];
    p.w6  = (const float*)d_in[19]; p.b6  = (const float*)d_in[20];
    p.w7  = (const float*)d_in[21]; p.b7  = (const float*)d_in[22];
    p.w8  = (const float*)d_in[23]; p.b8  = (const float*)d_in[24];
    p.w9  = (const float*)d_in[25]; p.b9  = (const float*)d_in[26];

    float* ws = (float*)d_ws;
    p.ebuf  = ws;                     // 23808
    p.L1R   = p.ebuf + 23808;         // 2*ZS1
    p.L2R   = p.L1R + 589824;
    p.L3R   = p.L2R + 589824;
    p.L4R   = p.L3R + 589824;
    p.MMR   = p.L4R + 589824;         // ZS1 (single)
    p.L5R   = p.MMR + 294912;
    p.L6R   = p.L5R + 294912;
    p.L7b   = p.L6R + 294912;         // 64*768
    p.L8b   = p.L7b + 49152;          // 16384
    p.preds = p.L8b + 16384;          // 12288
    p.bar   = (unsigned*)(p.preds + 12288);
    p.out   = (float*)d_out;

    hipMemsetAsync(p.bar, 0, 64 * sizeof(unsigned), stream);
    hipMemcpyAsync(p.ebuf, p.x, 23808 * sizeof(float), hipMemcpyDeviceToDevice, stream);

    const dim3 cb(64, 4);
    conv3B<<<dim3(1, 15, 8), 256, 0, stream>>>(p.ebuf, p.w1x, p.b1x, p.w1e, p.b1e, p.L1R);
    convYB<13, 15, 0, 1, 2><<<dim3(1, 13, 128), cb, 0, stream>>>(p.L1R, p.w2x, p.b2x, p.w2e, p.b2e, p.L2R);
    convYB<11, 13, 1, 2, 2><<<dim3(1, 11, 128), cb, 0, stream>>>(p.L2R, p.w3x, p.b3x, p.w3e, p.b3e, p.L3R);
    convYB<9, 11, 2, 3, 2><<<dim3(1, 9, 128), cb, 0, stream>>>(p.L3R, p.w4x, p.b4x, p.w4e, p.b4e, p.L4R);
    mmB<<<dim3(9, 8), 256, 0, stream>>>(p.L4R, p.MMR);
    convYB<7, 9, 3, 4, 1><<<dim3(1, 7, 64), cb, 0, stream>>>(p.MMR, p.w5, p.b5, p.w5, p.b5, p.L5R);
    convYB<5, 7, 4, 5, 1><<<dim3(1, 5, 64), cb, 0, stream>>>(p.L5R, p.w6, p.b6, p.w6, p.b6, p.L6R);

    stepper<<<NWG, cb, 0, stream>>>(p);
}